// Round 10
// baseline (812.162 us; speedup 1.0000x reference)
//
#include <hip/hip_runtime.h>
#include <hip/hip_bf16.h>

namespace {

constexpr int Bc = 64, Tc = 96, Fc = 48, Hc = 128, Ac = 8;
constexpr int DFFc = 512, DEMOc = 12, NHc = 4, Nc = 49, H3c = 384, DKc = 32;

typedef __attribute__((ext_vector_type(8))) short s8v;   // 8 bf16 = 4 VGPR (MFMA A/B frag)
typedef __attribute__((ext_vector_type(4))) float f4v;   // MFMA C/D frag

__device__ __forceinline__ float sigf(float x) { return 1.f / (1.f + expf(-x)); }
__device__ __forceinline__ float sigf_fast(float x) { return 1.f / (1.f + __expf(-x)); }
__device__ __forceinline__ float tanhf_fast(float x) {
  float e = __expf(2.f * x);
  return 1.f - 2.f / (e + 1.f);   // +-inf safe: ->1 / ->-1
}

__device__ __forceinline__ unsigned short f2b(float v) {   // fp32 -> bf16 bits (RNE)
  __hip_bfloat16 h = __float2bfloat16(v);
  union { __hip_bfloat16 b; unsigned short u; } c;
  c.b = h;
  return c.u;
}
__device__ __forceinline__ float b2f(unsigned short u) {
  union { unsigned u32; float f; } c;
  c.u32 = (unsigned)u << 16;
  return c.f;
}

// LDS-only barrier: does NOT drain vmcnt (global stores stay in flight).
// __syncthreads() emits s_waitcnt vmcnt(0) before s_barrier -> each GRU step
// stalled ~500-900cy on Hs store completion (r8: 4400cy/step vs ~700 modeled).
// rule #18: sched_barrier(0) fences around the asm waitcnt.
__device__ __forceinline__ void lds_barrier() {
  asm volatile("s_waitcnt lgkmcnt(0)" ::: "memory");
  __builtin_amdgcn_sched_barrier(0);
  __builtin_amdgcn_s_barrier();
  __builtin_amdgcn_sched_barrier(0);
}

// 4-partial unrolled dots (no fast-math -> compiler keeps serial chains; these
// cut the dependent-FMA depth 4x). a must be 16B-aligned LDS, w global (rows
// of 128/512 f32 are 16B aligned).
__device__ __forceinline__ float dot128(const float* __restrict__ a,
                                        const float* __restrict__ w) {
  float s0 = 0.f, s1 = 0.f, s2 = 0.f, s3 = 0.f;
#pragma unroll
  for (int k = 0; k < 128; k += 4) {
    float4 av = *reinterpret_cast<const float4*>(a + k);
    float4 wv = *reinterpret_cast<const float4*>(w + k);
    s0 += av.x * wv.x; s1 += av.y * wv.y; s2 += av.z * wv.z; s3 += av.w * wv.w;
  }
  return (s0 + s1) + (s2 + s3);
}
__device__ __forceinline__ float dot512(const float* __restrict__ a,
                                        const float* __restrict__ w) {
  float s0 = 0.f, s1 = 0.f, s2 = 0.f, s3 = 0.f;
#pragma unroll 8
  for (int k = 0; k < 512; k += 4) {
    float4 av = *reinterpret_cast<const float4*>(a + k);
    float4 wv = *reinterpret_cast<const float4*>(w + k);
    s0 += av.x * wv.x; s1 += av.y * wv.y; s2 += av.z * wv.z; s3 += av.w * wv.w;
  }
  return (s0 + s1) + (s2 + s3);
}

template <typename ST> __device__ __forceinline__ void stv(ST* p, float v);
template <> __device__ __forceinline__ void stv<float>(float* p, float v) { *p = v; }
template <> __device__ __forceinline__ void stv<__hip_bfloat16>(__hip_bfloat16* p, float v) {
  *p = __float2bfloat16(v);
}

template <typename ST> __device__ __forceinline__ void ld4(const ST* p, float* o);
template <> __device__ __forceinline__ void ld4<float>(const float* p, float* o) {
  float4 v = *reinterpret_cast<const float4*>(p);
  o[0] = v.x; o[1] = v.y; o[2] = v.z; o[3] = v.w;
}
template <> __device__ __forceinline__ void ld4<__hip_bfloat16>(const __hip_bfloat16* p, float* o) {
  ushort4 v = *reinterpret_cast<const ushort4*>(p);
  union { unsigned u; float f; } t;
  t.u = (unsigned)v.x << 16; o[0] = t.f;
  t.u = (unsigned)v.y << 16; o[1] = t.f;
  t.u = (unsigned)v.z << 16; o[2] = t.f;
  t.u = (unsigned)v.w << 16; o[3] = t.f;
}

// block reduce over nw waves (blockDim = nw*64); all threads must call
__device__ __forceinline__ float bsum(float v, float* red, int nw) {
#pragma unroll
  for (int off = 32; off > 0; off >>= 1) v += __shfl_down(v, off);
  int lane = threadIdx.x & 63, wid = threadIdx.x >> 6;
  __syncthreads();
  if (lane == 0) red[wid] = v;
  __syncthreads();
  float s = 0.f;
  for (int i = 0; i < nw; i++) s += red[i];
  return s;
}

// ---------------------------------------------------------------------------
// GRU scan via MFMA (r5; r8: 174us, MfmaUtil 21%, no spill — FETCH=9.4MB=one
// Whh pass). r9: in-loop __syncthreads -> lds_barrier (no vmcnt drain).
// ---------------------------------------------------------------------------
template <typename ST>
__global__ __launch_bounds__(512, 2) void gru_mfma(
    const float* __restrict__ x, const float* __restrict__ Wih,
    const float* __restrict__ Whh, const float* __restrict__ bih,
    const float* __restrict__ bhh, ST* __restrict__ Hs, float* __restrict__ hT) {
  const int f = blockIdx.x;
  const int b0 = blockIdx.y << 4;      // 16 batches per block
  const int tid = threadIdx.x;
  const int lane = tid & 63;
  const int w = tid >> 6;              // wave 0..7
  const int hh = (w << 4) + (lane & 15);  // this lane's h row (B-frag row & gate col)
  const int lg = lane >> 4;            // k-group 0..3

  s8v wh[12], wl[12];
#pragma unroll
  for (int gate = 0; gate < 3; gate++) {
#pragma unroll
    for (int ks = 0; ks < 4; ks++) {
      const float* wp = Whh + ((size_t)f * H3c + gate * Hc + hh) * Hc + (ks << 5) + (lg << 3);
      s8v hi, lo;
#pragma unroll
      for (int j = 0; j < 8; j++) {
        float v = wp[j];
        unsigned short hb = f2b(v);
        unsigned short lb = f2b(v - b2f(hb));
        hi[j] = (short)hb;
        lo[j] = (short)lb;
      }
      wh[gate * 4 + ks] = hi;
      wl[gate * 4 + ks] = lo;
    }
  }

  const float wi0 = Wih[f * H3c + hh], wi1 = Wih[f * H3c + Hc + hh], wi2 = Wih[f * H3c + 2 * Hc + hh];
  const float bi0 = bih[f * H3c + hh], bi1 = bih[f * H3c + Hc + hh], bi2 = bih[f * H3c + 2 * Hc + hh];
  const float bh0 = bhh[f * H3c + hh], bh1 = bhh[f * H3c + Hc + hh], bh2 = bhh[f * H3c + 2 * Hc + hh];

  __shared__ unsigned short hbuf[2][2][16 * 128];  // [buf][hi/lo][swizzled idx]
  __shared__ float xs[16][100];                    // x staged, padded stride

  {
    unsigned short* hz = &hbuf[0][0][0];
    for (int i = tid; i < 2 * 2 * 16 * 128; i += 512) hz[i] = 0;
    for (int i = tid; i < 16 * Tc; i += 512) {
      int b = i / Tc, t = i - b * Tc;
      xs[b][t] = x[((size_t)(b0 + b) * Tc + t) * Fc + f];
    }
  }
  __syncthreads();

  float hold[4] = {0.f, 0.f, 0.f, 0.f};  // fp32 master h for batches lg*4+r
  int cur = 0;

  for (int t = 0; t < Tc; t++) {
    s8v ahi[4], alo[4];
#pragma unroll
    for (int ks = 0; ks < 4; ks++) {
      int m = lane & 15;                                   // batch row
      int idx = m * 128 + ((((ks << 2) + lg) ^ (m & 7)) << 3);
      ahi[ks] = *reinterpret_cast<const s8v*>(&hbuf[cur][0][idx]);
      alo[ks] = *reinterpret_cast<const s8v*>(&hbuf[cur][1][idx]);
    }
    f4v accr = {0.f, 0.f, 0.f, 0.f}, accz = {0.f, 0.f, 0.f, 0.f}, accn = {0.f, 0.f, 0.f, 0.f};
#pragma unroll
    for (int ks = 0; ks < 4; ks++) {
      accr = __builtin_amdgcn_mfma_f32_16x16x32_bf16(ahi[ks], wh[0 + ks], accr, 0, 0, 0);
      accz = __builtin_amdgcn_mfma_f32_16x16x32_bf16(ahi[ks], wh[4 + ks], accz, 0, 0, 0);
      accn = __builtin_amdgcn_mfma_f32_16x16x32_bf16(ahi[ks], wh[8 + ks], accn, 0, 0, 0);
      accr = __builtin_amdgcn_mfma_f32_16x16x32_bf16(alo[ks], wh[0 + ks], accr, 0, 0, 0);
      accz = __builtin_amdgcn_mfma_f32_16x16x32_bf16(alo[ks], wh[4 + ks], accz, 0, 0, 0);
      accn = __builtin_amdgcn_mfma_f32_16x16x32_bf16(alo[ks], wh[8 + ks], accn, 0, 0, 0);
      accr = __builtin_amdgcn_mfma_f32_16x16x32_bf16(ahi[ks], wl[0 + ks], accr, 0, 0, 0);
      accz = __builtin_amdgcn_mfma_f32_16x16x32_bf16(ahi[ks], wl[4 + ks], accz, 0, 0, 0);
      accn = __builtin_amdgcn_mfma_f32_16x16x32_bf16(ahi[ks], wl[8 + ks], accn, 0, 0, 0);
    }
    int nxt = cur ^ 1;
#pragma unroll
    for (int r = 0; r < 4; r++) {
      int bt = (lg << 2) + r;  // batch within chunk (D row = (lane>>4)*4+reg)
      float xv = xs[bt][t];
      float rr = sigf_fast(xv * wi0 + bi0 + accr[r] + bh0);
      float zz = sigf_fast(xv * wi1 + bi1 + accz[r] + bh1);
      float nn = tanhf_fast(xv * wi2 + bi2 + rr * (accn[r] + bh2));
      float hn = (1.f - zz) * nn + zz * hold[r];
      hold[r] = hn;
      stv(&Hs[(((size_t)(b0 + bt) * Tc + t) * Fc + f) * Hc + hh], hn);
      unsigned short hb = f2b(hn);
      unsigned short lb = f2b(hn - b2f(hb));
      int widx = bt * 128 + (((hh >> 3) ^ (bt & 7)) << 3) + (hh & 7);
      hbuf[nxt][0][widx] = hb;
      hbuf[nxt][1][widx] = lb;
    }
    cur = nxt;
    lds_barrier();   // r9: LDS-only sync; Hs stores keep flying
  }
#pragma unroll
  for (int r = 0; r < 4; r++) {
    int bt = (lg << 2) + r;
    hT[((size_t)(b0 + bt) * Fc + f) * Hc + hh] = hold[r];
  }
}

// ---------------------------------------------------------------------------
// Kernel B: time-aware per-feature attention. Block per (f,b), 256 threads.
// r9: wave-parallel q-dot / max / sum (were 8-lane and tid==0 serial loops).
// ---------------------------------------------------------------------------
template <typename ST>
__global__ __launch_bounds__(256) void feat_attn(
    const ST* __restrict__ Hs, const float* __restrict__ hT,
    const float* __restrict__ Wt, const float* __restrict__ Wx,
    const float* __restrict__ rate, float* __restrict__ posi) {
  const int f = blockIdx.x, b = blockIdx.y;
  const int tid = threadIdx.x;
  const int lane = tid & 63, wid = tid >> 6;
  __shared__ float tile[Tc][Hc + 1];
  __shared__ float wxs[Hc][Ac];
  __shared__ float qs[Ac];
  __shared__ float es[Tc];
  __shared__ float qpart[2][Ac];
  __shared__ float red[4];
  __shared__ float inv_s;

  for (int i = tid; i < Tc * (Hc / 4); i += 256) {
    int t = i >> 5, k = (i & 31) << 2;
    float o[4];
    ld4(&Hs[(((size_t)b * Tc + t) * Fc + f) * Hc + k], o);
    tile[t][k] = o[0]; tile[t][k + 1] = o[1]; tile[t][k + 2] = o[2]; tile[t][k + 3] = o[3];
  }
  for (int i = tid; i < Hc * Ac; i += 256) (&wxs[0][0])[i] = Wx[(size_t)f * Hc * Ac + i];
  // q[a] = sum_h hT[h] * Wt[h][a], parallel over 128 lanes, shuffle-reduced
  if (tid < Hc) {
    float hv = hT[((size_t)b * Fc + f) * Hc + tid];
#pragma unroll
    for (int a = 0; a < Ac; a++) {
      float p = hv * Wt[((size_t)f * Hc + tid) * Ac + a];
#pragma unroll
      for (int off = 32; off > 0; off >>= 1) p += __shfl_down(p, off);
      if (lane == 0) qpart[wid][a] = p;
    }
  }
  __syncthreads();
  if (tid < Ac) qs[tid] = qpart[0][tid] + qpart[1][tid];
  __syncthreads();
  if (tid < Tc) {
    float ka[Ac];
#pragma unroll
    for (int a = 0; a < Ac; a++) ka[a] = 0.f;
    for (int h = 0; h < Hc; h++) {
      float hv = tile[tid][h];
#pragma unroll
      for (int a = 0; a < Ac; a++) ka[a] += hv * wxs[h][a];
    }
    float dot = 0.f;
#pragma unroll
    for (int a = 0; a < Ac; a++) dot += qs[a] * ka[a];
    float sd = sigf(dot);
    float denom = sigf(rate[f]) * (logf(2.72f + (1.f - sd)) * (float)(Tc - tid));
    es[tid] = fmaxf(sd / denom, 0.f);
  }
  __syncthreads();
  // parallel max over es[0..Tc)
  float mv = (tid < Tc) ? es[tid] : -1e30f;
#pragma unroll
  for (int off = 32; off > 0; off >>= 1) mv = fmaxf(mv, __shfl_down(mv, off));
  if (lane == 0) red[wid] = mv;
  __syncthreads();
  float m = fmaxf(fmaxf(red[0], red[1]), fmaxf(red[2], red[3]));
  float ev = (tid < Tc) ? __expf(es[tid] - m) : 0.f;
  if (tid < Tc) es[tid] = ev;
  // parallel sum
#pragma unroll
  for (int off = 32; off > 0; off >>= 1) ev += __shfl_down(ev, off);
  __syncthreads();
  if (lane == 0) red[wid] = ev;
  __syncthreads();
  if (tid == 0) inv_s = 1.f / (red[0] + red[1] + red[2] + red[3]);
  __syncthreads();
  if (tid < Hc) {
    float s0 = 0.f, s1 = 0.f, s2 = 0.f, s3 = 0.f;
#pragma unroll
    for (int t = 0; t < Tc; t += 4) {
      s0 += es[t] * tile[t][tid];
      s1 += es[t + 1] * tile[t + 1][tid];
      s2 += es[t + 2] * tile[t + 2][tid];
      s3 += es[t + 3] * tile[t + 3][tid];
    }
    posi[((size_t)b * Nc + f) * Hc + tid] = ((s0 + s1) + (s2 + s3)) * inv_s;
  }
}

// ---------------------------------------------------------------------------
__global__ __launch_bounds__(128) void demo_k(
    const float* __restrict__ demo, const float* __restrict__ dW,
    const float* __restrict__ db, float* __restrict__ posi) {
  int b = blockIdx.x, h = threadIdx.x;
  float acc = db[h];
  const float* dp = demo + b * DEMOc;
  const float* wp = dW + h * DEMOc;
#pragma unroll
  for (int d = 0; d < DEMOc; d++) acc += dp[d] * wp[d];
  posi[((size_t)b * Nc + (Nc - 1)) * Hc + h] = tanhf(acc);
}

__global__ __launch_bounds__(128) void ln_qkv(
    const float* __restrict__ posi, const float* __restrict__ ga, const float* __restrict__ be,
    const float* __restrict__ Wq, const float* __restrict__ bq,
    const float* __restrict__ Wk, const float* __restrict__ bk,
    const float* __restrict__ Wv, const float* __restrict__ bv,
    float* __restrict__ qb, float* __restrict__ kb, float* __restrict__ vb) {
  int bn = blockIdx.x;
  int b = bn / Nc, n = bn % Nc;
  int h = threadIdx.x;
  __shared__ __align__(16) float xn[Hc];
  __shared__ float red[2];
  float xv = posi[(size_t)bn * Hc + h];
  float m = bsum(xv, red, 2) * (1.f / Hc);
  float d = xv - m;
  float var = bsum(d * d, red, 2) * (1.f / (Hc - 1));
  xn[h] = ga[h] * d / (sqrtf(var) + 1e-7f) + be[h];
  __syncthreads();
  float q = bq[h] + dot128(xn, Wq + h * Hc);
  float k = bk[h] + dot128(xn, Wk + h * Hc);
  float v = bv[h] + dot128(xn, Wv + h * Hc);
  int head = h >> 5, dd = h & 31;
  size_t o = (((size_t)b * NHc + head) * Nc + n) * DKc + dd;
  qb[o] = q; kb[o] = k; vb[o] = v;
}

__global__ __launch_bounds__(64) void mha_attn(
    const float* __restrict__ qb, const float* __restrict__ kb,
    const float* __restrict__ vb, float* __restrict__ ctx) {
  int hd = blockIdx.x, b = blockIdx.y;
  int tid = threadIdx.x;
  __shared__ float ksm[Nc][DKc];
  __shared__ float vsm[Nc][DKc];
  __shared__ float sc[Nc][Nc];
  size_t base = ((size_t)b * NHc + hd) * Nc * DKc;
  for (int i = tid; i < Nc * DKc; i += 64) {
    ksm[i / DKc][i % DKc] = kb[base + i];
    vsm[i / DKc][i % DKc] = vb[base + i];
  }
  __syncthreads();
  if (tid < Nc) {
    float qr[DKc];
#pragma unroll
    for (int d = 0; d < DKc; d++) qr[d] = qb[base + tid * DKc + d];
    float mx = -1e30f;
    for (int mm = 0; mm < Nc; mm++) {
      float s = 0.f;
#pragma unroll
      for (int d = 0; d < DKc; d++) s += qr[d] * ksm[mm][d];
      s *= 0.17677669529663687f;  // 1/sqrt(32)
      sc[tid][mm] = s;
      mx = fmaxf(mx, s);
    }
    float ssum = 0.f;
    for (int mm = 0; mm < Nc; mm++) {
      float e = expf(sc[tid][mm] - mx);
      sc[tid][mm] = e;
      ssum += e;
    }
    float inv = 1.f / ssum;
    float acc[DKc];
#pragma unroll
    for (int d = 0; d < DKc; d++) acc[d] = 0.f;
    for (int mm = 0; mm < Nc; mm++) {
      float p = sc[tid][mm] * inv;
#pragma unroll
      for (int d = 0; d < DKc; d++) acc[d] += p * vsm[mm][d];
    }
    float* cp = ctx + ((size_t)b * Nc + tid) * Hc + hd * DKc;
#pragma unroll
    for (int d = 0; d < DKc; d++) cp[d] = acc[d];
  }
}

__global__ __launch_bounds__(128) void wo_res(
    const float* __restrict__ ctx, const float* __restrict__ Wo,
    const float* __restrict__ bo, const float* __restrict__ posi,
    float* __restrict__ mha, float* __restrict__ h1) {
  int bn = blockIdx.x;
  int h = threadIdx.x;
  __shared__ __align__(16) float cs[Hc];
  cs[h] = ctx[(size_t)bn * Hc + h];
  __syncthreads();
  float acc = bo[h] + dot128(cs, Wo + h * Hc);
  mha[(size_t)bn * Hc + h] = acc;
  h1[(size_t)bn * Hc + h] = posi[(size_t)bn * Hc + h] + acc;
}

// r9: grid (Nc, 4): each block computes a 32-row slice of the HxH cov matrix
// (r8: 49 blocks was latency-bound).
__global__ __launch_bounds__(512) void decov_k(
    const float* __restrict__ mha, float* __restrict__ dacc) {
  int n = blockIdx.x, q = blockIdx.y;
  int tid = threadIdx.x;
  __shared__ float xc[Bc][Hc];
  __shared__ float red[8];
  for (int i = tid; i < Bc * Hc; i += 512) {
    int b = i >> 7, h = i & 127;
    xc[b][h] = mha[((size_t)b * Nc + n) * Hc + h];
  }
  __syncthreads();
  if (tid < Hc) {
    float s = 0.f;
    for (int b = 0; b < Bc; b++) s += xc[b][tid];
    s *= (1.f / Bc);
    for (int b = 0; b < Bc; b++) xc[b][tid] -= s;
  }
  __syncthreads();
  float p2 = 0.f, pd = 0.f;
  for (int e = tid; e < 32 * Hc; e += 512) {
    int hh = (q << 5) + (e >> 7), gg = e & 127;
    float c0 = 0.f, c1 = 0.f, c2 = 0.f, c3 = 0.f;
#pragma unroll 4
    for (int b = 0; b < Bc; b += 4) {
      c0 += xc[b][hh] * xc[b][gg];
      c1 += xc[b + 1][hh] * xc[b + 1][gg];
      c2 += xc[b + 2][hh] * xc[b + 2][gg];
      c3 += xc[b + 3][hh] * xc[b + 3][gg];
    }
    float c = ((c0 + c1) + (c2 + c3)) * (1.f / (Bc - 1));
    float cc = c * c;
    p2 += cc;
    if (hh == gg) pd += cc;
  }
  float s2 = bsum(p2, red, 8);
  float sdg = bsum(pd, red, 8);
  if (tid == 0) atomicAdd(dacc, 0.5f * (s2 - sdg));
}

__global__ __launch_bounds__(256) void ln2_ffn1(
    const float* __restrict__ h1, const float* __restrict__ ga, const float* __restrict__ be,
    const float* __restrict__ W1, const float* __restrict__ b1, float* __restrict__ t1) {
  int bn = blockIdx.x;
  int tid = threadIdx.x;
  __shared__ __align__(16) float xn[Hc];
  __shared__ float red[4];
  float xv = (tid < Hc) ? h1[(size_t)bn * Hc + tid] : 0.f;
  float m = bsum(xv, red, 4) * (1.f / Hc);
  float d = (tid < Hc) ? (xv - m) : 0.f;
  float var = bsum(d * d, red, 4) * (1.f / (Hc - 1));
  if (tid < Hc) xn[tid] = ga[tid] * d / (sqrtf(var) + 1e-7f) + be[tid];
  __syncthreads();
#pragma unroll
  for (int jj = 0; jj < 2; jj++) {
    int j = tid + jj * 256;
    float acc = b1[j] + dot128(xn, W1 + j * Hc);
    t1[(size_t)bn * DFFc + j] = fmaxf(acc, 0.f);
  }
}

__global__ __launch_bounds__(128) void ffn2_res(
    const float* __restrict__ t1, const float* __restrict__ W2,
    const float* __restrict__ b2, const float* __restrict__ h1, float* __restrict__ h2) {
  int bn = blockIdx.x;
  int h = threadIdx.x;
  __shared__ __align__(16) float ts[DFFc];
  for (int i = h; i < DFFc; i += 128) ts[i] = t1[(size_t)bn * DFFc + i];
  __syncthreads();
  float acc = b2[h] + dot512(ts, W2 + h * DFFc);
  h2[(size_t)bn * Hc + h] = h1[(size_t)bn * Hc + h] + acc;
}

// ---------------------------------------------------------------------------
// r7 split of final_k (was 185us @1.5% occupancy). final_fkv: block per (b,n).
// ---------------------------------------------------------------------------
__global__ __launch_bounds__(128) void final_fkv(
    const float* __restrict__ h2,
    const float* __restrict__ Wk, const float* __restrict__ bk,
    const float* __restrict__ Wv, const float* __restrict__ bv,
    const float* __restrict__ Wq, const float* __restrict__ bq,
    float* __restrict__ fkb, float* __restrict__ fvb, float* __restrict__ fqb) {
  int bn = blockIdx.x;
  int b = bn / Nc, n = bn - b * Nc;
  int h = threadIdx.x;
  __shared__ __align__(16) float xs[Hc];
  xs[h] = h2[(size_t)bn * Hc + h];
  __syncthreads();
  fkb[(size_t)bn * Hc + h] = bk[h] + dot128(xs, Wk + h * Hc);
  fvb[(size_t)bn * Hc + h] = bv[h] + dot128(xs, Wv + h * Hc);
  if (n == Nc - 1) {
    fqb[(size_t)b * Hc + h] = bq[h] + dot128(xs, Wq + h * Hc);
  }
}

__global__ __launch_bounds__(128) void final2(
    const float* __restrict__ fkb, const float* __restrict__ fvb,
    const float* __restrict__ fqb,
    const float* __restrict__ oW, const float* __restrict__ ob,
    const float* __restrict__ dacc, float* __restrict__ out) {
  int b = blockIdx.x, h = threadIdx.x;
  int lane = h & 63, wid = h >> 6;
  __shared__ float fqs[Hc];
  __shared__ float alphas[Nc];
  __shared__ float red[2];
  __shared__ float r2[2];
  fqs[h] = fqb[(size_t)b * Hc + h];
  __syncthreads();
  // fe[n] = dot(fk[b,n,:], fq): wave-parallel, 64-lane shuffle dot (no barriers)
  for (int n = wid; n < Nc; n += 2) {
    const float* fkp = fkb + ((size_t)b * Nc + n) * Hc;
    float s = fkp[lane] * fqs[lane] + fkp[lane + 64] * fqs[lane + 64];
#pragma unroll
    for (int off = 32; off > 0; off >>= 1) s += __shfl_down(s, off);
    if (lane == 0) alphas[n] = s;
  }
  __syncthreads();
  if (h == 0) {
    float m = -1e30f;
    for (int n = 0; n < Nc; n++) m = fmaxf(m, alphas[n]);
    float ssum = 0.f;
    for (int n = 0; n < Nc; n++) {
      float e = expf(alphas[n] - m);
      alphas[n] = e;
      ssum += e;
    }
    red[0] = 1.f / ssum;
  }
  __syncthreads();
  float inv = red[0];
  // pooled[h] = sum_n alpha[n] * fv[b,n,h]   (fv reads coalesced across h)
  float pv = 0.f;
  for (int n = 0; n < Nc; n++) pv += alphas[n] * fvb[((size_t)b * Nc + n) * Hc + h];
  pv *= inv;
  float c = pv * oW[h];
#pragma unroll
  for (int off = 32; off > 0; off >>= 1) c += __shfl_down(c, off);
  if (lane == 0) r2[wid] = c;
  __syncthreads();
  if (h == 0) {
    out[b] = sigf(r2[0] + r2[1] + ob[0]);
    if (b == 0) out[Bc] = dacc[0];
  }
}

}  // namespace

extern "C" void kernel_launch(void* const* d_in, const int* in_sizes, int n_in,
                              void* d_out, int out_size, void* d_ws, size_t ws_size,
                              hipStream_t stream) {
  const float* x    = (const float*)d_in[0];
  const float* demo = (const float*)d_in[1];
  const float* gWih = (const float*)d_in[2];
  const float* gWhh = (const float*)d_in[3];
  const float* gbih = (const float*)d_in[4];
  const float* gbhh = (const float*)d_in[5];
  const float* aWt  = (const float*)d_in[6];
  const float* aWx  = (const float*)d_in[7];
  const float* aRt  = (const float*)d_in[8];
  const float* dW   = (const float*)d_in[9];
  const float* db   = (const float*)d_in[10];
  const float* mWq  = (const float*)d_in[11];
  const float* mbq  = (const float*)d_in[12];
  const float* mWk  = (const float*)d_in[13];
  const float* mbk  = (const float*)d_in[14];
  const float* mWv  = (const float*)d_in[15];
  const float* mbv  = (const float*)d_in[16];
  const float* mWo  = (const float*)d_in[17];
  const float* mbo  = (const float*)d_in[18];
  const float* l1a  = (const float*)d_in[19];
  const float* l1b  = (const float*)d_in[20];
  const float* l2a  = (const float*)d_in[21];
  const float* l2b  = (const float*)d_in[22];
  const float* fW1  = (const float*)d_in[23];
  const float* fb1  = (const float*)d_in[24];
  const float* fW2  = (const float*)d_in[25];
  const float* fb2  = (const float*)d_in[26];
  const float* fWq  = (const float*)d_in[27];
  const float* fbq  = (const float*)d_in[28];
  const float* fWk  = (const float*)d_in[29];
  const float* fbk  = (const float*)d_in[30];
  const float* fWv  = (const float*)d_in[31];
  const float* fbv  = (const float*)d_in[32];
  const float* oW   = (const float*)d_in[33];
  const float* ob   = (const float*)d_in[34];

  char* base = (char*)d_ws;
  size_t off = 0;
  auto take = [&](size_t nfloats) -> float* {
    float* r = (float*)(base + off);
    off += ((nfloats * sizeof(float)) + 255) & ~(size_t)255;
    return r;
  };
  float* dec  = take(64);
  float* hT   = take((size_t)Bc * Fc * Hc);
  float* posi = take((size_t)Bc * Nc * Hc);
  float* qb   = take((size_t)Bc * Nc * Hc);
  float* kb   = take((size_t)Bc * Nc * Hc);
  float* vb   = take((size_t)Bc * Nc * Hc);
  float* ctx  = take((size_t)Bc * Nc * Hc);
  float* mha  = take((size_t)Bc * Nc * Hc);
  float* h1   = take((size_t)Bc * Nc * Hc);
  float* t1   = take((size_t)Bc * Nc * DFFc);
  float* h2   = take((size_t)Bc * Nc * Hc);
  float* fkb  = take((size_t)Bc * Nc * Hc);
  float* fvb  = take((size_t)Bc * Nc * Hc);
  float* fqb  = take((size_t)Bc * Hc);
  size_t HsElems = (size_t)Bc * Tc * Fc * Hc;  // 37.7M
  void* HsPtr = (void*)(base + off);
  bool f32path = (ws_size >= off + HsElems * sizeof(float));

  hipMemsetAsync(dec, 0, sizeof(float), stream);

  dim3 gGru(Fc, Bc / 16);
  dim3 gAtt(Fc, Bc);
  if (f32path) {
    gru_mfma<float><<<gGru, 512, 0, stream>>>(x, gWih, gWhh, gbih, gbhh, (float*)HsPtr, hT);
    feat_attn<float><<<gAtt, 256, 0, stream>>>((const float*)HsPtr, hT, aWt, aWx, aRt, posi);
  } else {
    gru_mfma<__hip_bfloat16><<<gGru, 512, 0, stream>>>(x, gWih, gWhh, gbih, gbhh,
                                                       (__hip_bfloat16*)HsPtr, hT);
    feat_attn<__hip_bfloat16><<<gAtt, 256, 0, stream>>>((const __hip_bfloat16*)HsPtr, hT,
                                                        aWt, aWx, aRt, posi);
  }
  demo_k<<<Bc, 128, 0, stream>>>(demo, dW, db, posi);
  ln_qkv<<<Bc * Nc, 128, 0, stream>>>(posi, l1a, l1b, mWq, mbq, mWk, mbk, mWv, mbv, qb, kb, vb);
  mha_attn<<<dim3(NHc, Bc), 64, 0, stream>>>(qb, kb, vb, ctx);
  wo_res<<<Bc * Nc, 128, 0, stream>>>(ctx, mWo, mbo, posi, mha, h1);
  decov_k<<<dim3(Nc, 4), 512, 0, stream>>>(mha, dec);
  ln2_ffn1<<<Bc * Nc, 256, 0, stream>>>(h1, l2a, l2b, fW1, fb1, t1);
  ffn2_res<<<Bc * Nc, 128, 0, stream>>>(t1, fW2, fb2, h1, h2);
  final_fkv<<<Bc * Nc, 128, 0, stream>>>(h2, fWk, fbk, fWv, fbv, fWq, fbq, fkb, fvb, fqb);
  final2<<<Bc, 128, 0, stream>>>(fkb, fvb, fqb, oW, ob, dec, (float*)d_out);
}